// Round 9
// baseline (207.565 us; speedup 1.0000x reference)
//
#include <hip/hip_runtime.h>

#define N_NODES 50000
#define N_EDGES 800000
#define D 128
#define NBUCKET 196       // col>>8 in [0,196)
#define CAP 8192          // fixed bucket capacity (Poisson mean 4096, +64 sigma)
#define EPT 16            // edges per thread in scatter
#define SCAT_BLOCKS 196   // ceil(N_EDGES/EPT/256)
#define GEMM_TILES 782    // ceil(N_NODES/64)
#define GEMM_BLOCKS (GEMM_TILES * 3)   // one block per (tile, mat): single-barrier blocks
#define AGG_UNITS 12500   // N_NODES/4
#define AGG_BLOCKS 2048   // grid-stride (G11): avoids 12500-block dispatch overhead

typedef unsigned short ushort_t;
typedef __bf16 bf16x8 __attribute__((ext_vector_type(8)));
typedef float f32x4 __attribute__((ext_vector_type(4)));
typedef float f32x2 __attribute__((ext_vector_type(2)));

__device__ __forceinline__ ushort_t f2bf(float f) {
    unsigned u = __builtin_bit_cast(unsigned, f);
    u += 0x7FFFu + ((u >> 16) & 1u);   // round-to-nearest-even
    return (ushort_t)(u >> 16);
}
__device__ __forceinline__ float bf2f(unsigned h16) {
    return __builtin_bit_cast(float, h16 << 16);
}
__device__ __forceinline__ bf16x8 pack8(float4 p0, float4 p1) {
    ushort_t __attribute__((aligned(16))) t[8] =
        { f2bf(p0.x), f2bf(p0.y), f2bf(p0.z), f2bf(p0.w),
          f2bf(p1.x), f2bf(p1.y), f2bf(p1.z), f2bf(p1.w) };
    return __builtin_bit_cast(bf16x8, *(const uint4*)t);
}

// ---------- bucket scatter only (wconv eliminated: GEMMs now stage W f32->bf16 in-LDS) ----------
// temp entry: row (16b, N_NODES<65536) | (col&255)<<16
__global__ __launch_bounds__(256) void k_pre(const int* __restrict__ row, const int* __restrict__ col,
                                             int* __restrict__ bucket_cursor, unsigned* __restrict__ temp) {
    __shared__ int hist[NBUCKET];
    int b = blockIdx.x;
    for (int t = threadIdx.x; t < NBUCKET; t += 256) hist[t] = 0;
    __syncthreads();
    int base = (b * 256 + threadIdx.x) * EPT;
    bool act = base < N_EDGES;
    int4 c[4], r[4];
    if (act) {
        #pragma unroll
        for (int q = 0; q < 4; ++q) c[q] = *(const int4*)(col + base + q * 4);
        #pragma unroll
        for (int q = 0; q < 4; ++q) r[q] = *(const int4*)(row + base + q * 4);
        #pragma unroll
        for (int q = 0; q < 4; ++q) {
            atomicAdd(&hist[c[q].x >> 8], 1); atomicAdd(&hist[c[q].y >> 8], 1);
            atomicAdd(&hist[c[q].z >> 8], 1); atomicAdd(&hist[c[q].w >> 8], 1);
        }
    }
    __syncthreads();
    for (int t = threadIdx.x; t < NBUCKET; t += 256) {
        int cnt = hist[t];
        hist[t] = cnt ? atomicAdd(&bucket_cursor[t], cnt) : 0;  // block base within bucket
    }
    __syncthreads();
    if (act) {
        #pragma unroll
        for (int q = 0; q < 4; ++q) {
            int cc[4] = { c[q].x, c[q].y, c[q].z, c[q].w };
            int rr[4] = { r[q].x, r[q].y, r[q].z, r[q].w };
            #pragma unroll
            for (int e = 0; e < 4; ++e) {
                int bk = cc[e] >> 8;
                int pos = atomicAdd(&hist[bk], 1);   // LDS rank -> slot within bucket
                temp[bk * CAP + pos] = (unsigned)rr[e] | ((unsigned)(cc[e] & 255) << 16);
            }
        }
    }
}

// ---------- GEMM block: ONE (tile, mat) pair -> single barrier, no y-loop serialization.
// mat 0 = W1 (-> Plb), 1 = W2 left (-> Pi), 2 = W2 right (-> Pj8 fp8, opt. pre-scaled).
// B staged f32->bf16 directly from W1s/W2s (L2-resident; Wb/wconv pass eliminated).
// A per-lane direct from global (zero cross-lane reuse under this MFMA mapping);
// A-loads issue before the barrier, overlapping B staging. M=64, one 16-row sub-tile/wave.
// NO min-waves clamp (R5: clamp forced scratch; 134us cold dispatch). ----------
template<bool AF32>
__device__ __forceinline__ void gemm_tile_mat(int tile, int mat, ushort_t (*Bs)[136],
                                              const void* __restrict__ xsrc,
                                              const float* __restrict__ W1f,   // layer's W1 [128][128]
                                              const float* __restrict__ W2f,   // layer's W2 [128][256]
                                              const float* __restrict__ scl,   // null: Pj unscaled
                                              ushort_t* __restrict__ Plb,
                                              ushort_t* __restrict__ Pi_,
                                              unsigned char* __restrict__ Pj8) {
    const int tid = threadIdx.x;
    const int w = tid >> 6, lane = tid & 63, quad = lane >> 4, r16 = lane & 15;
    const int gm = tile * 64 + w * 16 + r16;
    // stage B: f32 -> bf16 in-flight
    #pragma unroll
    for (int it = 0; it < 8; ++it) {
        int c = tid + it * 256;
        int r = c >> 4, kc = c & 15;
        const float* src = (mat == 0) ? (W1f + r * 128 + kc * 8)
                                      : (W2f + r * 256 + (mat == 2 ? 128 : 0) + kc * 8);
        float4 p0 = *(const float4*)src;
        float4 p1 = *(const float4*)(src + 4);
        *(uint4*)&Bs[r][kc * 8] = __builtin_bit_cast(uint4, pack8(p0, p1));
    }
    // A fragments (independent of LDS -> overlap with staging before the barrier)
    bf16x8 a[4];
    if constexpr (AF32) {
        const float* xf = (const float*)xsrc;
        #pragma unroll
        for (int kk = 0; kk < 4; ++kk) {
            int colc = kk * 32 + quad * 8;
            float4 p0 = {0.f,0.f,0.f,0.f}, p1 = {0.f,0.f,0.f,0.f};
            if (gm < N_NODES) {
                p0 = *(const float4*)(xf + (size_t)gm * D + colc);
                p1 = *(const float4*)(xf + (size_t)gm * D + colc + 4);
            }
            a[kk] = pack8(p0, p1);
        }
    } else {
        const ushort_t* xb = (const ushort_t*)xsrc;
        #pragma unroll
        for (int kk = 0; kk < 4; ++kk) {
            int colc = kk * 32 + quad * 8;
            uint4 v0 = make_uint4(0,0,0,0);
            if (gm < N_NODES) v0 = *(const uint4*)(xb + (size_t)gm * D + colc);
            a[kk] = __builtin_bit_cast(bf16x8, v0);
        }
    }
    __syncthreads();
    f32x4 acc[8];
    #pragma unroll
    for (int nt = 0; nt < 8; ++nt) acc[nt] = (f32x4){0.f, 0.f, 0.f, 0.f};
    #pragma unroll
    for (int kk = 0; kk < 4; ++kk) {
        #pragma unroll
        for (int nt = 0; nt < 8; ++nt) {
            bf16x8 b = __builtin_bit_cast(bf16x8,
                *(const uint4*)&Bs[nt * 16 + r16][kk * 32 + quad * 8]);
            acc[nt] = __builtin_amdgcn_mfma_f32_16x16x32_bf16(b, a[kk], acc[nt], 0, 0, 0);
        }
    }
    if (gm < N_NODES) {
        if (mat < 2) {
            ushort_t* Outp = (mat == 0) ? Plb : Pi_;
            #pragma unroll
            for (int nt = 0; nt < 8; ++nt) {
                ushort_t tmp[4] = { f2bf(acc[nt][0]), f2bf(acc[nt][1]),
                                    f2bf(acc[nt][2]), f2bf(acc[nt][3]) };
                *(uint2*)(Outp + (size_t)gm * D + nt * 16 + quad * 4) = *(const uint2*)tmp;
            }
        } else {
            float sc = scl ? scl[gm] : 1.0f;
            #pragma unroll
            for (int nt = 0; nt < 8; ++nt) {
                int v = __builtin_amdgcn_cvt_pk_fp8_f32(acc[nt][0] * sc, acc[nt][1] * sc, 0, false);
                v = __builtin_amdgcn_cvt_pk_fp8_f32(acc[nt][2] * sc, acc[nt][3] * sc, v, true);
                *(unsigned*)(Pj8 + (size_t)gm * D + nt * 16 + quad * 4) = (unsigned)v;
            }
        }
    }
}

// LDS union for k_bsort_gemm: sort blocks use hist/sm, gemm blocks use Bs (34816 B total)
union __align__(16) LdsBG {
    ushort_t Bs[128][136];
    struct { int hist[256]; int sm[256]; } s;
};

// ---------- fused: per-bucket sort (first 196 blocks) + layer-0 GEMM mat-blocks (rest) ----------
__global__ __launch_bounds__(256) void k_bsort_gemm(const unsigned* __restrict__ temp,
                                                    const int* __restrict__ bucket_cursor, // = counts
                                                    ushort_t* __restrict__ csr, int* __restrict__ off,
                                                    int* __restrict__ deg, float* __restrict__ inv_deg,
                                                    const float* __restrict__ xf,
                                                    const float* __restrict__ W1s,
                                                    const float* __restrict__ W2s,
                                                    ushort_t* __restrict__ Plb,
                                                    ushort_t* __restrict__ Pi_,
                                                    unsigned char* __restrict__ Pj8) {
    __shared__ LdsBG lds;
    if (blockIdx.x < NBUCKET) {
        int* hist = lds.s.hist;
        int* sm = lds.s.sm;
        int b = blockIdx.x, t = threadIdx.x;
        int cnt = bucket_cursor[b];
        // global CSR base = sum of counts of buckets < b
        sm[t] = (t < b) ? bucket_cursor[t] : 0;
        __syncthreads();
        for (int o = 1; o < 256; o <<= 1) {
            int add = (t >= o) ? sm[t - o] : 0;
            __syncthreads();
            sm[t] += add;
            __syncthreads();
        }
        int gbase = sm[255];
        int tbase = b * CAP;
        hist[t] = 0;
        __syncthreads();
        int i = t;
        for (; i + 768 < cnt; i += 1024) {      // 4 loads in flight
            unsigned e0 = temp[tbase + i], e1 = temp[tbase + i + 256];
            unsigned e2 = temp[tbase + i + 512], e3 = temp[tbase + i + 768];
            atomicAdd(&hist[e0 >> 16], 1); atomicAdd(&hist[e1 >> 16], 1);
            atomicAdd(&hist[e2 >> 16], 1); atomicAdd(&hist[e3 >> 16], 1);
        }
        for (; i < cnt; i += 256) atomicAdd(&hist[temp[tbase + i] >> 16], 1);
        __syncthreads();
        int c = hist[t];
        sm[t] = c;
        __syncthreads();
        for (int o = 1; o < 256; o <<= 1) {
            int add = (t >= o) ? sm[t - o] : 0;
            __syncthreads();
            sm[t] += add;
            __syncthreads();
        }
        int excl = sm[t] - c;
        int node = b * 256 + t;
        if (node < N_NODES) {
            off[node] = gbase + excl;
            deg[node] = c;
            inv_deg[node] = 1.0f / (float)c;    // deg >= 1 by construction
        }
        __syncthreads();
        hist[t] = gbase + excl;                 // per-col cursor
        __syncthreads();
        i = t;
        for (; i + 768 < cnt; i += 1024) {
            unsigned e0 = temp[tbase + i], e1 = temp[tbase + i + 256];
            unsigned e2 = temp[tbase + i + 512], e3 = temp[tbase + i + 768];
            int p0 = atomicAdd(&hist[e0 >> 16], 1);
            int p1 = atomicAdd(&hist[e1 >> 16], 1);
            int p2 = atomicAdd(&hist[e2 >> 16], 1);
            int p3 = atomicAdd(&hist[e3 >> 16], 1);
            csr[p0] = (ushort_t)e0; csr[p1] = (ushort_t)e1;
            csr[p2] = (ushort_t)e2; csr[p3] = (ushort_t)e3;
        }
        for (; i < cnt; i += 256) {
            unsigned e = temp[tbase + i];
            int p = atomicAdd(&hist[e >> 16], 1);
            csr[p] = (ushort_t)e;
        }
    } else {
        // layer 0: mat-inner ordering -> 3 consecutive blocks share A-rows (L2-hot).
        // inv_deg not yet available (computed concurrently) -> Pj unscaled; A from f32 x.
        int gid = blockIdx.x - NBUCKET;
        gemm_tile_mat<true>(gid / 3, gid % 3, lds.Bs, xf, W1s, W2s, nullptr, Plb, Pi_, Pj8);
    }
}

// ---------- standalone GEMM (layer 1): A from bf16 xb, inv_deg available -> Pj pre-scaled ----------
__global__ __launch_bounds__(256) void k_gemm(const ushort_t* __restrict__ xb,
                                              const float* __restrict__ W1f,
                                              const float* __restrict__ W2f,
                                              const float* __restrict__ inv_deg,
                                              ushort_t* __restrict__ Plb,
                                              ushort_t* __restrict__ Pi_,
                                              unsigned char* __restrict__ Pj8) {
    __shared__ __align__(16) ushort_t Bs[128][136];
    gemm_tile_mat<false>(blockIdx.x / 3, blockIdx.x % 3, Bs, xb, W1f, W2f, inv_deg, Plb, Pi_, Pj8);
}

// ---------- aggregation + exact GELU.
// Single fully-predicated 32-edge batch (8 groups x 4 edges): all gathers issue together ->
// one memory round-trip for deg<=32 (P ~ 0.9998, Poisson(16)). Inactive groups clamp to the
// last edge (L1-hit) with weight 0 -> exact sums. Grid-stride over units (G11: 2048 blocks).
template<int LAYER0>
__device__ __forceinline__ void agg_unit(int u,
                                         const ushort_t* __restrict__ Plb,
                                         const ushort_t* __restrict__ Pi_,
                                         const unsigned char* __restrict__ Pj8,
                                         const int* __restrict__ off,
                                         const int* __restrict__ deg,
                                         const ushort_t* __restrict__ csr,
                                         const float* __restrict__ inv_deg,
                                         const float* __restrict__ bias,
                                         float* __restrict__ s_arr,
                                         float* __restrict__ out_f32,
                                         ushort_t* __restrict__ out_bf16) {
    int wv = __builtin_amdgcn_readfirstlane(threadIdx.x >> 6);   // wave-uniform node
    int node = u * 4 + wv;                 // AGG_UNITS*4 == N_NODES exactly
    const int lane = threadIdx.x & 63;
    const int g = lane >> 4;      // edge slot within quad
    const int q8 = lane & 15;     // element octet
    const int eoff = 8 * q8 + 2 * g;
    unsigned ulin = *(const unsigned*)(Plb + (size_t)node * D + eoff);
    unsigned upi  = *(const unsigned*)(Pi_ + (size_t)node * D + eoff);
    float2 bv = *(const float2*)(bias + eoff);
    float su[8];
    #pragma unroll
    for (int k = 0; k < 8; ++k) su[k] = 0.f;
    float sd = 0.f;
    const int e0 = off[node], ne = deg[node];
    for (int j = 0; j < ne; j += 32) {
        int sx[8];
        float wt[8];
        #pragma unroll
        for (int t = 0; t < 8; ++t) {
            int idx = j + 4 * t + g;
            bool a = idx < ne;
            sx[t] = csr[e0 + (a ? idx : ne - 1)];
            wt[t] = a ? 1.f : 0.f;
        }
        uint2 uu[8];
        #pragma unroll
        for (int t = 0; t < 8; ++t) uu[t] = *(const uint2*)(Pj8 + (size_t)sx[t] * D + 8 * q8);
        float dv[8];
        if (LAYER0) {
            #pragma unroll
            for (int t = 0; t < 8; ++t) dv[t] = inv_deg[sx[t]] * wt[t];
        } else {
            #pragma unroll
            for (int t = 0; t < 8; ++t) dv[t] = wt[t];
        }
        #pragma unroll
        for (int t = 0; t < 8; ++t) {
            f32x2 f0 = __builtin_amdgcn_cvt_pk_f32_fp8((int)uu[t].x, false);
            f32x2 f1 = __builtin_amdgcn_cvt_pk_f32_fp8((int)uu[t].x, true);
            f32x2 f2 = __builtin_amdgcn_cvt_pk_f32_fp8((int)uu[t].y, false);
            f32x2 f3 = __builtin_amdgcn_cvt_pk_f32_fp8((int)uu[t].y, true);
            if (LAYER0) sd += dv[t];
            su[0] += dv[t] * f0[0]; su[1] += dv[t] * f0[1];
            su[2] += dv[t] * f1[0]; su[3] += dv[t] * f1[1];
            su[4] += dv[t] * f2[0]; su[5] += dv[t] * f2[1];
            su[6] += dv[t] * f3[0]; su[7] += dv[t] * f3[1];
        }
    }
    // combine the 4 edge-groups: butterfly over lane bits 4 and 5
    #pragma unroll
    for (int k = 0; k < 8; ++k) {
        su[k] += __shfl_xor(su[k], 16);
        su[k] += __shfl_xor(su[k], 32);
    }
    float si;
    if (LAYER0) {
        sd += __shfl_xor(sd, 16);
        sd += __shfl_xor(sd, 32);
        si = sd;
        if (lane == 0) s_arr[node] = si;
    } else {
        si = s_arr[node];
    }
    float t0 = (g < 2) ? ((g == 0) ? su[0] : su[2]) : ((g == 2) ? su[4] : su[6]);
    float t1 = (g < 2) ? ((g == 0) ? su[1] : su[3]) : ((g == 2) ? su[5] : su[7]);
    float a0 = bf2f(ulin & 0xffffu) + bv.x - si * bf2f(upi & 0xffffu) - t0;
    float a1 = bf2f(ulin >> 16)     + bv.y - si * bf2f(upi >> 16)     - t1;
    float g0 = 0.5f * a0 * (1.0f + erff(a0 * 0.70710678118654752440f));
    float g1 = 0.5f * a1 * (1.0f + erff(a1 * 0.70710678118654752440f));
    if (LAYER0) {
        ushort_t tmp[2] = { f2bf(g0), f2bf(g1) };
        *(unsigned*)(out_bf16 + (size_t)node * D + eoff) = *(const unsigned*)tmp;
    } else {
        *(float2*)(out_f32 + (size_t)node * D + eoff) = make_float2(g0, g1);
    }
}

__global__ __launch_bounds__(256) void k_agg0(const ushort_t* __restrict__ Plb,
                                              const ushort_t* __restrict__ Pi_,
                                              const unsigned char* __restrict__ Pj8,
                                              const int* __restrict__ off,
                                              const int* __restrict__ deg,
                                              const ushort_t* __restrict__ csr,
                                              const float* __restrict__ inv_deg,
                                              const float* __restrict__ bias,
                                              float* __restrict__ s_arr,
                                              ushort_t* __restrict__ out_bf16) {
    for (int u = blockIdx.x; u < AGG_UNITS; u += AGG_BLOCKS)
        agg_unit<1>(u, Plb, Pi_, Pj8, off, deg, csr, inv_deg, bias, s_arr, nullptr, out_bf16);
}

__global__ __launch_bounds__(256) void k_agg1(const ushort_t* __restrict__ Plb,
                                              const ushort_t* __restrict__ Pi_,
                                              const unsigned char* __restrict__ Pj8,
                                              const int* __restrict__ off,
                                              const int* __restrict__ deg,
                                              const ushort_t* __restrict__ csr,
                                              const float* __restrict__ inv_deg,
                                              const float* __restrict__ bias,
                                              float* __restrict__ s_arr,
                                              float* __restrict__ out_f32) {
    for (int u = blockIdx.x; u < AGG_UNITS; u += AGG_BLOCKS)
        agg_unit<0>(u, Plb, Pi_, Pj8, off, deg, csr, inv_deg, bias, s_arr, out_f32, nullptr);
}

extern "C" void kernel_launch(void* const* d_in, const int* in_sizes, int n_in,
                              void* d_out, int out_size, void* d_ws, size_t ws_size,
                              hipStream_t stream) {
    const float* x      = (const float*)d_in[0];
    const int*   ei     = (const int*)d_in[1];
    const int*   rowp   = ei;
    const int*   colp   = ei + N_EDGES;
    const float* W1s    = (const float*)d_in[2];
    const float* W2s    = (const float*)d_in[3];
    const float* biases = (const float*)d_in[4];
    float* out = (float*)d_out;

    char* ws = (char*)d_ws;
    size_t o = 0;
    auto carve = [&](size_t bytes) -> void* {
        void* p = ws + o;
        o = (o + bytes + 255) & ~(size_t)255;
        return p;
    };
    int*           bucket_cursor = (int*)carve(NBUCKET * 4);
    int*           deg     = (int*)carve(N_NODES * 4);
    float*         inv_deg = (float*)carve(N_NODES * 4);
    int*           off     = (int*)carve(N_NODES * 4);
    float*         s_arr   = (float*)carve(N_NODES * 4);
    ushort_t*      csr     = (ushort_t*)carve((size_t)N_EDGES * 2);
    unsigned*      temp    = (unsigned*)carve((size_t)NBUCKET * CAP * 4);
    ushort_t*      xb      = (ushort_t*)carve((size_t)N_NODES * D * 2);
    ushort_t*      Plb     = (ushort_t*)carve((size_t)N_NODES * D * 2);
    ushort_t*      Pi_     = (ushort_t*)carve((size_t)N_NODES * D * 2);
    unsigned char* Pj8     = (unsigned char*)carve((size_t)N_NODES * D);
    if (o > ws_size) return;   // diagnostic: absmax would read exactly 10.875

    hipMemsetAsync(bucket_cursor, 0, NBUCKET * 4, stream);

    k_pre<<<SCAT_BLOCKS, 256, 0, stream>>>(rowp, colp, bucket_cursor, temp);
    k_bsort_gemm<<<NBUCKET + GEMM_BLOCKS, 256, 0, stream>>>(temp, bucket_cursor, csr, off,
                                                            deg, inv_deg, x, W1s, W2s,
                                                            Plb, Pi_, Pj8);

    k_agg0<<<AGG_BLOCKS, 256, 0, stream>>>(Plb, Pi_, Pj8, off, deg, csr, inv_deg, biases,
                                           s_arr, xb);
    k_gemm<<<GEMM_BLOCKS, 256, 0, stream>>>(xb, W1s + 16384, W2s + 32768, inv_deg,
                                            Plb, Pi_, Pj8);
    k_agg1<<<AGG_BLOCKS, 256, 0, stream>>>(Plb, Pi_, Pj8, off, deg, csr, inv_deg, biases + 128,
                                           s_arr, out);
}

// Round 10
// 198.049 us; speedup vs baseline: 1.0480x; 1.0480x over previous
//
#include <hip/hip_runtime.h>

#define N_NODES 50000
#define N_EDGES 800000
#define D 128
#define NBUCKET 196       // col>>8 in [0,196)
#define CAP 8192          // fixed bucket capacity (Poisson mean 4096, +64 sigma)
#define EPT 16            // edges per thread in scatter
#define SCAT_BLOCKS 196   // ceil(N_EDGES/EPT/256)
#define WCONV_BLOCKS 96   // 2*3*16384 floats / 4 / 256
#define GEMM_TILES 782    // ceil(N_NODES/64)  -- M=64 tiles (R7 win)

typedef unsigned short ushort_t;
typedef __bf16 bf16x8 __attribute__((ext_vector_type(8)));
typedef float f32x4 __attribute__((ext_vector_type(4)));
typedef float f32x2 __attribute__((ext_vector_type(2)));

__device__ __forceinline__ ushort_t f2bf(float f) {
    unsigned u = __builtin_bit_cast(unsigned, f);
    u += 0x7FFFu + ((u >> 16) & 1u);   // round-to-nearest-even
    return (ushort_t)(u >> 16);
}
__device__ __forceinline__ float bf2f(unsigned h16) {
    return __builtin_bit_cast(float, h16 << 16);
}
__device__ __forceinline__ bf16x8 pack8(float4 p0, float4 p1) {
    ushort_t __attribute__((aligned(16))) t[8] =
        { f2bf(p0.x), f2bf(p0.y), f2bf(p0.z), f2bf(p0.w),
          f2bf(p1.x), f2bf(p1.y), f2bf(p1.z), f2bf(p1.w) };
    return __builtin_bit_cast(bf16x8, *(const uint4*)t);
}

// ---------- fused: bucket scatter + weight cast (R8 structure: Wb bf16 precompute beats
// per-GEMM-block f32 staging -- R9 A/B evidence). temp entry: row(16b) | (col&255)<<16 ----------
__global__ __launch_bounds__(256) void k_pre(const int* __restrict__ row, const int* __restrict__ col,
                                             int* __restrict__ bucket_cursor, unsigned* __restrict__ temp,
                                             const float* __restrict__ W1s, const float* __restrict__ W2s,
                                             ushort_t* __restrict__ Wb) {
    __shared__ int hist[NBUCKET];
    int b = blockIdx.x;
    if (b < SCAT_BLOCKS) {
        for (int t = threadIdx.x; t < NBUCKET; t += 256) hist[t] = 0;
        __syncthreads();
        int base = (b * 256 + threadIdx.x) * EPT;
        bool act = base < N_EDGES;
        int4 c[4], r[4];
        if (act) {
            #pragma unroll
            for (int q = 0; q < 4; ++q) c[q] = *(const int4*)(col + base + q * 4);
            #pragma unroll
            for (int q = 0; q < 4; ++q) r[q] = *(const int4*)(row + base + q * 4);
            #pragma unroll
            for (int q = 0; q < 4; ++q) {
                atomicAdd(&hist[c[q].x >> 8], 1); atomicAdd(&hist[c[q].y >> 8], 1);
                atomicAdd(&hist[c[q].z >> 8], 1); atomicAdd(&hist[c[q].w >> 8], 1);
            }
        }
        __syncthreads();
        for (int t = threadIdx.x; t < NBUCKET; t += 256) {
            int cnt = hist[t];
            hist[t] = cnt ? atomicAdd(&bucket_cursor[t], cnt) : 0;  // block base within bucket
        }
        __syncthreads();
        if (act) {
            #pragma unroll
            for (int q = 0; q < 4; ++q) {
                int cc[4] = { c[q].x, c[q].y, c[q].z, c[q].w };
                int rr[4] = { r[q].x, r[q].y, r[q].z, r[q].w };
                #pragma unroll
                for (int e = 0; e < 4; ++e) {
                    int bk = cc[e] >> 8;
                    int pos = atomicAdd(&hist[bk], 1);   // LDS rank -> slot within bucket
                    temp[bk * CAP + pos] = (unsigned)rr[e] | ((unsigned)(cc[e] & 255) << 16);
                }
            }
        }
    } else {
        // Wb layout: [(k*3 + mat)][128][128] bf16, mat 0=W1, 1=W2 left, 2=W2 right
        int c = (b - SCAT_BLOCKS) * 256 + threadIdx.x;   // float4 chunk, [0, 24576)
        int k = c / 12288, rem = c % 12288;
        int mat = rem / 4096, rr = (rem % 4096) / 32, col4 = rem % 32;
        const float* src = (mat == 0)
            ? (W1s + k * 16384 + rr * 128 + col4 * 4)
            : (W2s + k * 32768 + rr * 256 + (mat == 2 ? 128 : 0) + col4 * 4);
        float4 v = *(const float4*)src;
        ushort_t tmp[4] = { f2bf(v.x), f2bf(v.y), f2bf(v.z), f2bf(v.w) };
        *(uint2*)(Wb + ((size_t)(k * 3 + mat)) * 16384 + rr * 128 + col4 * 4) = *(const uint2*)tmp;
    }
}

// ---------- GEMM tile, M=64 (one 16-row sub-tile per wave; 782 tiles ~= 3 blocks/CU).
// A per-lane direct from global (zero cross-lane reuse under this MFMA mapping);
// B in LDS from bf16 Wb (128-way reuse). 3-mat y-loop keeps A-frags in registers across mats
// (R9 showed splitting mats into blocks costs more in A/B traffic than barriers save).
// NO min-waves clamp (R5: clamp forced scratch codegen, 134us cold dispatch). ----------
template<bool AF32>
__device__ __forceinline__ void gemm_tile3(int m0, ushort_t (*Bs)[136],
                                           const void* __restrict__ xsrc,
                                           const ushort_t* __restrict__ Wl,
                                           const float* __restrict__ scl,
                                           ushort_t* __restrict__ Plb,
                                           ushort_t* __restrict__ Pi_,
                                           unsigned char* __restrict__ Pj8) {
    const int tid = threadIdx.x;
    const int w = tid >> 6, lane = tid & 63, quad = lane >> 4, r16 = lane & 15;
    const int gm = m0 + w * 16 + r16;       // one 16-row sub-tile per wave
    bf16x8 a[4];
    if constexpr (AF32) {
        const float* xf = (const float*)xsrc;
        #pragma unroll
        for (int kk = 0; kk < 4; ++kk) {
            int colc = kk * 32 + quad * 8;
            float4 p0 = {0.f,0.f,0.f,0.f}, p1 = {0.f,0.f,0.f,0.f};
            if (gm < N_NODES) {
                p0 = *(const float4*)(xf + (size_t)gm * D + colc);
                p1 = *(const float4*)(xf + (size_t)gm * D + colc + 4);
            }
            a[kk] = pack8(p0, p1);
        }
    } else {
        const ushort_t* xb = (const ushort_t*)xsrc;
        #pragma unroll
        for (int kk = 0; kk < 4; ++kk) {
            int colc = kk * 32 + quad * 8;
            uint4 v0 = make_uint4(0,0,0,0);
            if (gm < N_NODES) v0 = *(const uint4*)(xb + (size_t)gm * D + colc);
            a[kk] = __builtin_bit_cast(bf16x8, v0);
        }
    }
    #pragma unroll
    for (int y = 0; y < 3; ++y) {
        const ushort_t* Wmat = Wl + (size_t)y * 16384;
        #pragma unroll
        for (int it = 0; it < 8; ++it) {
            int c = tid + it * 256;
            int r = c >> 4, kc = c & 15;
            *(uint4*)&Bs[r][kc * 8] = *(const uint4*)(Wmat + r * 128 + kc * 8);
        }
        __syncthreads();
        f32x4 acc[8];
        #pragma unroll
        for (int nt = 0; nt < 8; ++nt) acc[nt] = (f32x4){0.f, 0.f, 0.f, 0.f};
        #pragma unroll
        for (int kk = 0; kk < 4; ++kk) {
            #pragma unroll
            for (int nt = 0; nt < 8; ++nt) {
                bf16x8 b = __builtin_bit_cast(bf16x8,
                    *(const uint4*)&Bs[nt * 16 + r16][kk * 32 + quad * 8]);
                acc[nt] = __builtin_amdgcn_mfma_f32_16x16x32_bf16(b, a[kk], acc[nt], 0, 0, 0);
            }
        }
        if (gm < N_NODES) {
            if (y < 2) {
                ushort_t* Outp = (y == 0) ? Plb : Pi_;
                #pragma unroll
                for (int nt = 0; nt < 8; ++nt) {
                    ushort_t tmp[4] = { f2bf(acc[nt][0]), f2bf(acc[nt][1]),
                                        f2bf(acc[nt][2]), f2bf(acc[nt][3]) };
                    *(uint2*)(Outp + (size_t)gm * D + nt * 16 + quad * 4) = *(const uint2*)tmp;
                }
            } else {
                float sc = scl ? scl[gm] : 1.0f;
                #pragma unroll
                for (int nt = 0; nt < 8; ++nt) {
                    int v = __builtin_amdgcn_cvt_pk_fp8_f32(acc[nt][0] * sc, acc[nt][1] * sc, 0, false);
                    v = __builtin_amdgcn_cvt_pk_fp8_f32(acc[nt][2] * sc, acc[nt][3] * sc, v, true);
                    *(unsigned*)(Pj8 + (size_t)gm * D + nt * 16 + quad * 4) = (unsigned)v;
                }
            }
        }
        if (y < 2) __syncthreads();   // protect Bs overwrite (A-frags live in registers)
    }
}

// LDS union for k_bsort_gemm: sort blocks use hist/sm, gemm blocks use Bs (34816 B total)
union __align__(16) LdsBG {
    ushort_t Bs[128][136];
    struct { int hist[256]; int sm[256]; } s;
};

// ---------- fused: per-bucket sort (first 196 blocks) + layer-0 GEMM (rest) ----------
__global__ __launch_bounds__(256) void k_bsort_gemm(const unsigned* __restrict__ temp,
                                                    const int* __restrict__ bucket_cursor, // = counts
                                                    ushort_t* __restrict__ csr, int* __restrict__ off,
                                                    int* __restrict__ deg, float* __restrict__ inv_deg,
                                                    const float* __restrict__ xf,
                                                    const ushort_t* __restrict__ Wb,
                                                    ushort_t* __restrict__ Plb,
                                                    ushort_t* __restrict__ Pi_,
                                                    unsigned char* __restrict__ Pj8) {
    __shared__ LdsBG lds;
    if (blockIdx.x < NBUCKET) {
        int* hist = lds.s.hist;
        int* sm = lds.s.sm;
        int b = blockIdx.x, t = threadIdx.x;
        int cnt = bucket_cursor[b];
        // global CSR base = sum of counts of buckets < b
        sm[t] = (t < b) ? bucket_cursor[t] : 0;
        __syncthreads();
        for (int o = 1; o < 256; o <<= 1) {
            int add = (t >= o) ? sm[t - o] : 0;
            __syncthreads();
            sm[t] += add;
            __syncthreads();
        }
        int gbase = sm[255];
        int tbase = b * CAP;
        hist[t] = 0;
        __syncthreads();
        int i = t;
        for (; i + 768 < cnt; i += 1024) {      // 4 loads in flight
            unsigned e0 = temp[tbase + i], e1 = temp[tbase + i + 256];
            unsigned e2 = temp[tbase + i + 512], e3 = temp[tbase + i + 768];
            atomicAdd(&hist[e0 >> 16], 1); atomicAdd(&hist[e1 >> 16], 1);
            atomicAdd(&hist[e2 >> 16], 1); atomicAdd(&hist[e3 >> 16], 1);
        }
        for (; i < cnt; i += 256) atomicAdd(&hist[temp[tbase + i] >> 16], 1);
        __syncthreads();
        int c = hist[t];
        sm[t] = c;
        __syncthreads();
        for (int o = 1; o < 256; o <<= 1) {
            int add = (t >= o) ? sm[t - o] : 0;
            __syncthreads();
            sm[t] += add;
            __syncthreads();
        }
        int excl = sm[t] - c;
        int node = b * 256 + t;
        if (node < N_NODES) {
            off[node] = gbase + excl;
            deg[node] = c;
            inv_deg[node] = 1.0f / (float)c;    // deg >= 1 by construction
        }
        __syncthreads();
        hist[t] = gbase + excl;                 // per-col cursor
        __syncthreads();
        i = t;
        for (; i + 768 < cnt; i += 1024) {
            unsigned e0 = temp[tbase + i], e1 = temp[tbase + i + 256];
            unsigned e2 = temp[tbase + i + 512], e3 = temp[tbase + i + 768];
            int p0 = atomicAdd(&hist[e0 >> 16], 1);
            int p1 = atomicAdd(&hist[e1 >> 16], 1);
            int p2 = atomicAdd(&hist[e2 >> 16], 1);
            int p3 = atomicAdd(&hist[e3 >> 16], 1);
            csr[p0] = (ushort_t)e0; csr[p1] = (ushort_t)e1;
            csr[p2] = (ushort_t)e2; csr[p3] = (ushort_t)e3;
        }
        for (; i < cnt; i += 256) {
            unsigned e = temp[tbase + i];
            int p = atomicAdd(&hist[e >> 16], 1);
            csr[p] = (ushort_t)e;
        }
    } else {
        // layer 0: inv_deg not yet available (computed concurrently) -> Pj unscaled; A from f32 x
        gemm_tile3<true>((blockIdx.x - NBUCKET) * 64, lds.Bs, xf, Wb, nullptr, Plb, Pi_, Pj8);
    }
}

// ---------- standalone GEMM (layer 1): A from bf16 xb, inv_deg available -> Pj pre-scaled ----------
__global__ __launch_bounds__(256) void k_gemm(const ushort_t* __restrict__ xb,
                                              const ushort_t* __restrict__ Wl,
                                              const float* __restrict__ inv_deg,
                                              ushort_t* __restrict__ Plb,
                                              ushort_t* __restrict__ Pi_,
                                              unsigned char* __restrict__ Pj8) {
    __shared__ __align__(16) ushort_t Bs[128][136];
    gemm_tile3<false>(blockIdx.x * 64, Bs, xb, Wl, inv_deg, Plb, Pi_, Pj8);
}

// ---------- aggregation + exact GELU.
// Single fully-predicated 32-edge batch per iteration: ALL loads (csr idx, row gathers,
// inv_deg) issue together -> one memory round-trip for deg<=32 (P ~ 0.9998, Poisson(16)).
// NEW (R9 counter evidence: VALUBusy ~50%): per-slot guard `if (j+4t < ne)` skips the
// cvt/fma arithmetic for slots entirely past the degree (wave-uniform branch) -- typical
// deg=16 node executes 4 of 8 slots instead of all 8, halving agg VALU. Boundary slots
// still use per-lane wt masking; skipped slots contributed exactly 0 -> numerics identical.
// One wave per node, 12500 blocks (R9 lesson: grid-stride serialization hurt; TLP wins).
template<int LAYER0>
__device__ __forceinline__ void agg_body(const ushort_t* __restrict__ Plb,
                                         const ushort_t* __restrict__ Pi_,
                                         const unsigned char* __restrict__ Pj8,
                                         const int* __restrict__ off,
                                         const int* __restrict__ deg,
                                         const ushort_t* __restrict__ csr,
                                         const float* __restrict__ inv_deg,
                                         const float* __restrict__ bias,
                                         float* __restrict__ s_arr,
                                         float* __restrict__ out_f32,
                                         ushort_t* __restrict__ out_bf16) {
    int wv = __builtin_amdgcn_readfirstlane(threadIdx.x >> 6);   // wave-uniform node
    int node = blockIdx.x * 4 + wv;
    if (node >= N_NODES) return;
    const int lane = threadIdx.x & 63;
    const int g = lane >> 4;      // edge slot within quad
    const int q8 = lane & 15;     // element octet
    const int eoff = 8 * q8 + 2 * g;
    unsigned ulin = *(const unsigned*)(Plb + (size_t)node * D + eoff);
    unsigned upi  = *(const unsigned*)(Pi_ + (size_t)node * D + eoff);
    float2 bv = *(const float2*)(bias + eoff);
    float su[8];
    #pragma unroll
    for (int k = 0; k < 8; ++k) su[k] = 0.f;
    float sd = 0.f;
    const int e0 = off[node], ne = deg[node];
    for (int j = 0; j < ne; j += 32) {
        int sx[8];
        float wt[8];
        #pragma unroll
        for (int t = 0; t < 8; ++t) {
            int idx = j + 4 * t + g;
            bool a = idx < ne;
            sx[t] = csr[e0 + (a ? idx : ne - 1)];
            wt[t] = a ? 1.f : 0.f;
        }
        uint2 uu[8];
        #pragma unroll
        for (int t = 0; t < 8; ++t) uu[t] = *(const uint2*)(Pj8 + (size_t)sx[t] * D + 8 * q8);
        float dv[8];
        if (LAYER0) {
            #pragma unroll
            for (int t = 0; t < 8; ++t) dv[t] = inv_deg[sx[t]] * wt[t];
        } else {
            #pragma unroll
            for (int t = 0; t < 8; ++t) dv[t] = wt[t];
        }
        #pragma unroll
        for (int t = 0; t < 8; ++t) {
            if (j + 4 * t < ne) {   // wave-uniform skip of fully-inactive slots
                f32x2 f0 = __builtin_amdgcn_cvt_pk_f32_fp8((int)uu[t].x, false);
                f32x2 f1 = __builtin_amdgcn_cvt_pk_f32_fp8((int)uu[t].x, true);
                f32x2 f2 = __builtin_amdgcn_cvt_pk_f32_fp8((int)uu[t].y, false);
                f32x2 f3 = __builtin_amdgcn_cvt_pk_f32_fp8((int)uu[t].y, true);
                if (LAYER0) sd += dv[t];
                su[0] += dv[t] * f0[0]; su[1] += dv[t] * f0[1];
                su[2] += dv[t] * f1[0]; su[3] += dv[t] * f1[1];
                su[4] += dv[t] * f2[0]; su[5] += dv[t] * f2[1];
                su[6] += dv[t] * f3[0]; su[7] += dv[t] * f3[1];
            }
        }
    }
    // combine the 4 edge-groups: butterfly over lane bits 4 and 5
    #pragma unroll
    for (int k = 0; k < 8; ++k) {
        su[k] += __shfl_xor(su[k], 16);
        su[k] += __shfl_xor(su[k], 32);
    }
    float si;
    if (LAYER0) {
        sd += __shfl_xor(sd, 16);
        sd += __shfl_xor(sd, 32);
        si = sd;
        if (lane == 0) s_arr[node] = si;
    } else {
        si = s_arr[node];
    }
    float t0 = (g < 2) ? ((g == 0) ? su[0] : su[2]) : ((g == 2) ? su[4] : su[6]);
    float t1 = (g < 2) ? ((g == 0) ? su[1] : su[3]) : ((g == 2) ? su[5] : su[7]);
    float a0 = bf2f(ulin & 0xffffu) + bv.x - si * bf2f(upi & 0xffffu) - t0;
    float a1 = bf2f(ulin >> 16)     + bv.y - si * bf2f(upi >> 16)     - t1;
    float g0 = 0.5f * a0 * (1.0f + erff(a0 * 0.70710678118654752440f));
    float g1 = 0.5f * a1 * (1.0f + erff(a1 * 0.70710678118654752440f));
    if (LAYER0) {
        ushort_t tmp[2] = { f2bf(g0), f2bf(g1) };
        *(unsigned*)(out_bf16 + (size_t)node * D + eoff) = *(const unsigned*)tmp;
    } else {
        *(float2*)(out_f32 + (size_t)node * D + eoff) = make_float2(g0, g1);
    }
}

__global__ __launch_bounds__(256) void k_agg0(const ushort_t* __restrict__ Plb,
                                              const ushort_t* __restrict__ Pi_,
                                              const unsigned char* __restrict__ Pj8,
                                              const int* __restrict__ off,
                                              const int* __restrict__ deg,
                                              const ushort_t* __restrict__ csr,
                                              const float* __restrict__ inv_deg,
                                              const float* __restrict__ bias,
                                              float* __restrict__ s_arr,
                                              ushort_t* __restrict__ out_bf16) {
    agg_body<1>(Plb, Pi_, Pj8, off, deg, csr, inv_deg, bias, s_arr, nullptr, out_bf16);
}

__global__ __launch_bounds__(256) void k_agg1(const ushort_t* __restrict__ Plb,
                                              const ushort_t* __restrict__ Pi_,
                                              const unsigned char* __restrict__ Pj8,
                                              const int* __restrict__ off,
                                              const int* __restrict__ deg,
                                              const ushort_t* __restrict__ csr,
                                              const float* __restrict__ inv_deg,
                                              const float* __restrict__ bias,
                                              float* __restrict__ s_arr,
                                              float* __restrict__ out_f32) {
    agg_body<0>(Plb, Pi_, Pj8, off, deg, csr, inv_deg, bias, s_arr, out_f32, nullptr);
}

extern "C" void kernel_launch(void* const* d_in, const int* in_sizes, int n_in,
                              void* d_out, int out_size, void* d_ws, size_t ws_size,
                              hipStream_t stream) {
    const float* x      = (const float*)d_in[0];
    const int*   ei     = (const int*)d_in[1];
    const int*   rowp   = ei;
    const int*   colp   = ei + N_EDGES;
    const float* W1s    = (const float*)d_in[2];
    const float* W2s    = (const float*)d_in[3];
    const float* biases = (const float*)d_in[4];
    float* out = (float*)d_out;

    char* ws = (char*)d_ws;
    size_t o = 0;
    auto carve = [&](size_t bytes) -> void* {
        void* p = ws + o;
        o = (o + bytes + 255) & ~(size_t)255;
        return p;
    };
    int*           bucket_cursor = (int*)carve(NBUCKET * 4);
    int*           deg     = (int*)carve(N_NODES * 4);
    float*         inv_deg = (float*)carve(N_NODES * 4);
    int*           off     = (int*)carve(N_NODES * 4);
    float*         s_arr   = (float*)carve(N_NODES * 4);
    ushort_t*      csr     = (ushort_t*)carve((size_t)N_EDGES * 2);
    unsigned*      temp    = (unsigned*)carve((size_t)NBUCKET * CAP * 4);
    ushort_t*      xb      = (ushort_t*)carve((size_t)N_NODES * D * 2);
    ushort_t*      Wb      = (ushort_t*)carve((size_t)2 * 3 * 16384 * 2);
    ushort_t*      Plb     = (ushort_t*)carve((size_t)N_NODES * D * 2);
    ushort_t*      Pi_     = (ushort_t*)carve((size_t)N_NODES * D * 2);
    unsigned char* Pj8     = (unsigned char*)carve((size_t)N_NODES * D);
    if (o > ws_size) return;   // diagnostic: absmax would read exactly 10.875

    hipMemsetAsync(bucket_cursor, 0, NBUCKET * 4, stream);

    k_pre<<<SCAT_BLOCKS + WCONV_BLOCKS, 256, 0, stream>>>(rowp, colp, bucket_cursor, temp,
                                                          W1s, W2s, Wb);
    k_bsort_gemm<<<NBUCKET + GEMM_TILES, 256, 0, stream>>>(temp, bucket_cursor, csr, off,
                                                           deg, inv_deg, x, Wb, Plb, Pi_, Pj8);

    const int AB = (N_NODES + 3) / 4;
    k_agg0<<<AB, 256, 0, stream>>>(Plb, Pi_, Pj8, off, deg, csr, inv_deg, biases, s_arr, xb);
    k_gemm<<<GEMM_TILES, 256, 0, stream>>>(xb, Wb + (size_t)3 * 16384, inv_deg, Plb, Pi_, Pj8);
    k_agg1<<<AB, 256, 0, stream>>>(Plb, Pi_, Pj8, off, deg, csr, inv_deg, biases + 128, s_arr, out);
}

// Round 11
// 191.995 us; speedup vs baseline: 1.0811x; 1.0315x over previous
//
#include <hip/hip_runtime.h>

#define N_NODES 50000
#define N_EDGES 800000
#define D 128
#define NBUCKET 196       // col>>8 in [0,196)
#define CAP 8192          // fixed bucket capacity (Poisson mean 4096, +64 sigma)
#define EPT 16            // edges per thread in scatter
#define SCAT_BLOCKS 196   // ceil(N_EDGES/EPT/256)
#define WCONV_BLOCKS 96   // 2*3*16384 floats / 4 / 256
#define GEMM_TILES 782    // ceil(N_NODES/64)  -- M=64 tiles for balance + occupancy

typedef unsigned short ushort_t;
typedef __bf16 bf16x8 __attribute__((ext_vector_type(8)));
typedef float f32x4 __attribute__((ext_vector_type(4)));
typedef float f32x2 __attribute__((ext_vector_type(2)));

__device__ __forceinline__ ushort_t f2bf(float f) {
    unsigned u = __builtin_bit_cast(unsigned, f);
    u += 0x7FFFu + ((u >> 16) & 1u);   // round-to-nearest-even
    return (ushort_t)(u >> 16);
}
__device__ __forceinline__ float bf2f(unsigned h16) {
    return __builtin_bit_cast(float, h16 << 16);
}
__device__ __forceinline__ bf16x8 pack8(float4 p0, float4 p1) {
    ushort_t __attribute__((aligned(16))) t[8] =
        { f2bf(p0.x), f2bf(p0.y), f2bf(p0.z), f2bf(p0.w),
          f2bf(p1.x), f2bf(p1.y), f2bf(p1.z), f2bf(p1.w) };
    return __builtin_bit_cast(bf16x8, *(const uint4*)t);
}

// ---------- fused: bucket scatter (LDS-rank, fixed-cap buckets, packed 4B entries) + weight cast ----------
// temp entry: row (16b, N_NODES<65536) | (col&255)<<16
__global__ __launch_bounds__(256) void k_pre(const int* __restrict__ row, const int* __restrict__ col,
                                             int* __restrict__ bucket_cursor, unsigned* __restrict__ temp,
                                             const float* __restrict__ W1s, const float* __restrict__ W2s,
                                             ushort_t* __restrict__ Wb) {
    __shared__ int hist[NBUCKET];
    int b = blockIdx.x;
    if (b < SCAT_BLOCKS) {
        for (int t = threadIdx.x; t < NBUCKET; t += 256) hist[t] = 0;
        __syncthreads();
        int base = (b * 256 + threadIdx.x) * EPT;
        bool act = base < N_EDGES;
        int4 c[4], r[4];
        if (act) {
            #pragma unroll
            for (int q = 0; q < 4; ++q) c[q] = *(const int4*)(col + base + q * 4);
            #pragma unroll
            for (int q = 0; q < 4; ++q) r[q] = *(const int4*)(row + base + q * 4);
            #pragma unroll
            for (int q = 0; q < 4; ++q) {
                atomicAdd(&hist[c[q].x >> 8], 1); atomicAdd(&hist[c[q].y >> 8], 1);
                atomicAdd(&hist[c[q].z >> 8], 1); atomicAdd(&hist[c[q].w >> 8], 1);
            }
        }
        __syncthreads();
        for (int t = threadIdx.x; t < NBUCKET; t += 256) {
            int cnt = hist[t];
            hist[t] = cnt ? atomicAdd(&bucket_cursor[t], cnt) : 0;  // block base within bucket
        }
        __syncthreads();
        if (act) {
            #pragma unroll
            for (int q = 0; q < 4; ++q) {
                int cc[4] = { c[q].x, c[q].y, c[q].z, c[q].w };
                int rr[4] = { r[q].x, r[q].y, r[q].z, r[q].w };
                #pragma unroll
                for (int e = 0; e < 4; ++e) {
                    int bk = cc[e] >> 8;
                    int pos = atomicAdd(&hist[bk], 1);   // LDS rank -> slot within bucket
                    temp[bk * CAP + pos] = (unsigned)rr[e] | ((unsigned)(cc[e] & 255) << 16);
                }
            }
        }
    } else {
        // Wb layout: [(k*3 + mat)][128][128] bf16, mat 0=W1, 1=W2 left, 2=W2 right
        int c = (b - SCAT_BLOCKS) * 256 + threadIdx.x;   // float4 chunk, [0, 24576)
        int k = c / 12288, rem = c % 12288;
        int mat = rem / 4096, rr = (rem % 4096) / 32, col4 = rem % 32;
        const float* src = (mat == 0)
            ? (W1s + k * 16384 + rr * 128 + col4 * 4)
            : (W2s + k * 32768 + rr * 256 + (mat == 2 ? 128 : 0) + col4 * 4);
        float4 v = *(const float4*)src;
        ushort_t tmp[4] = { f2bf(v.x), f2bf(v.y), f2bf(v.z), f2bf(v.w) };
        *(uint2*)(Wb + ((size_t)(k * 3 + mat)) * 16384 + rr * 128 + col4 * 4) = *(const uint2*)tmp;
    }
}

// ---------- GEMM tile, M=64 (one 16-row sub-tile per wave; 782 tiles ~= 3.8 blocks/CU).
// A has ZERO cross-lane reuse under this MFMA fragment mapping -> A-fragments load per-lane
// direct from global into registers (f32->bf16 in-reg for layer 0). B in LDS (128-way reuse).
// NO min-waves clamp (R5 lesson: clamp forced scratch codegen, 134us cold dispatch).
// y=0/1 -> bf16 Plb/Pi; y=2 -> FP8 e4m3 Pj (optionally pre-scaled by inv_deg). ----------
template<bool AF32>
__device__ __forceinline__ void gemm_tile3(int m0, ushort_t (*Bs)[136],
                                           const void* __restrict__ xsrc,
                                           const ushort_t* __restrict__ Wl,
                                           const float* __restrict__ scl,
                                           ushort_t* __restrict__ Plb,
                                           ushort_t* __restrict__ Pi_,
                                           unsigned char* __restrict__ Pj8) {
    const int tid = threadIdx.x;
    const int w = tid >> 6, lane = tid & 63, quad = lane >> 4, r16 = lane & 15;
    const int gm = m0 + w * 16 + r16;       // one 16-row sub-tile per wave
    bf16x8 a[4];
    if constexpr (AF32) {
        const float* xf = (const float*)xsrc;
        #pragma unroll
        for (int kk = 0; kk < 4; ++kk) {
            int colc = kk * 32 + quad * 8;
            float4 p0 = {0.f,0.f,0.f,0.f}, p1 = {0.f,0.f,0.f,0.f};
            if (gm < N_NODES) {
                p0 = *(const float4*)(xf + (size_t)gm * D + colc);
                p1 = *(const float4*)(xf + (size_t)gm * D + colc + 4);
            }
            a[kk] = pack8(p0, p1);
        }
    } else {
        const ushort_t* xb = (const ushort_t*)xsrc;
        #pragma unroll
        for (int kk = 0; kk < 4; ++kk) {
            int colc = kk * 32 + quad * 8;
            uint4 v0 = make_uint4(0,0,0,0);
            if (gm < N_NODES) v0 = *(const uint4*)(xb + (size_t)gm * D + colc);
            a[kk] = __builtin_bit_cast(bf16x8, v0);
        }
    }
    #pragma unroll
    for (int y = 0; y < 3; ++y) {
        const ushort_t* Wmat = Wl + (size_t)y * 16384;
        #pragma unroll
        for (int it = 0; it < 8; ++it) {
            int c = tid + it * 256;
            int r = c >> 4, kc = c & 15;
            *(uint4*)&Bs[r][kc * 8] = *(const uint4*)(Wmat + r * 128 + kc * 8);
        }
        __syncthreads();
        f32x4 acc[8];
        #pragma unroll
        for (int nt = 0; nt < 8; ++nt) acc[nt] = (f32x4){0.f, 0.f, 0.f, 0.f};
        #pragma unroll
        for (int kk = 0; kk < 4; ++kk) {
            #pragma unroll
            for (int nt = 0; nt < 8; ++nt) {
                bf16x8 b = __builtin_bit_cast(bf16x8,
                    *(const uint4*)&Bs[nt * 16 + r16][kk * 32 + quad * 8]);
                acc[nt] = __builtin_amdgcn_mfma_f32_16x16x32_bf16(b, a[kk], acc[nt], 0, 0, 0);
            }
        }
        if (gm < N_NODES) {
            if (y < 2) {
                ushort_t* Outp = (y == 0) ? Plb : Pi_;
                #pragma unroll
                for (int nt = 0; nt < 8; ++nt) {
                    ushort_t tmp[4] = { f2bf(acc[nt][0]), f2bf(acc[nt][1]),
                                        f2bf(acc[nt][2]), f2bf(acc[nt][3]) };
                    *(uint2*)(Outp + (size_t)gm * D + nt * 16 + quad * 4) = *(const uint2*)tmp;
                }
            } else {
                float sc = scl ? scl[gm] : 1.0f;
                #pragma unroll
                for (int nt = 0; nt < 8; ++nt) {
                    int v = __builtin_amdgcn_cvt_pk_fp8_f32(acc[nt][0] * sc, acc[nt][1] * sc, 0, false);
                    v = __builtin_amdgcn_cvt_pk_fp8_f32(acc[nt][2] * sc, acc[nt][3] * sc, v, true);
                    *(unsigned*)(Pj8 + (size_t)gm * D + nt * 16 + quad * 4) = (unsigned)v;
                }
            }
        }
        if (y < 2) __syncthreads();   // protect Bs overwrite (A-frags live in registers)
    }
}

// LDS union for k_bsort_gemm: sort blocks use hist/sm, gemm blocks use Bs (34816 B total)
union __align__(16) LdsBG {
    ushort_t Bs[128][136];
    struct { int hist[256]; int sm[256]; } s;
};

// ---------- fused: per-bucket sort (first 196 blocks) + layer-0 GEMM (rest) ----------
__global__ __launch_bounds__(256) void k_bsort_gemm(const unsigned* __restrict__ temp,
                                                    const int* __restrict__ bucket_cursor, // = counts
                                                    ushort_t* __restrict__ csr, int* __restrict__ off,
                                                    int* __restrict__ deg, float* __restrict__ inv_deg,
                                                    const float* __restrict__ xf,
                                                    const ushort_t* __restrict__ Wb,
                                                    ushort_t* __restrict__ Plb,
                                                    ushort_t* __restrict__ Pi_,
                                                    unsigned char* __restrict__ Pj8) {
    __shared__ LdsBG lds;
    if (blockIdx.x < NBUCKET) {
        int* hist = lds.s.hist;
        int* sm = lds.s.sm;
        int b = blockIdx.x, t = threadIdx.x;
        int cnt = bucket_cursor[b];
        // global CSR base = sum of counts of buckets < b
        sm[t] = (t < b) ? bucket_cursor[t] : 0;
        __syncthreads();
        for (int o = 1; o < 256; o <<= 1) {
            int add = (t >= o) ? sm[t - o] : 0;
            __syncthreads();
            sm[t] += add;
            __syncthreads();
        }
        int gbase = sm[255];
        int tbase = b * CAP;
        hist[t] = 0;
        __syncthreads();
        int i = t;
        for (; i + 768 < cnt; i += 1024) {      // 4 loads in flight
            unsigned e0 = temp[tbase + i], e1 = temp[tbase + i + 256];
            unsigned e2 = temp[tbase + i + 512], e3 = temp[tbase + i + 768];
            atomicAdd(&hist[e0 >> 16], 1); atomicAdd(&hist[e1 >> 16], 1);
            atomicAdd(&hist[e2 >> 16], 1); atomicAdd(&hist[e3 >> 16], 1);
        }
        for (; i < cnt; i += 256) atomicAdd(&hist[temp[tbase + i] >> 16], 1);
        __syncthreads();
        int c = hist[t];
        sm[t] = c;
        __syncthreads();
        for (int o = 1; o < 256; o <<= 1) {
            int add = (t >= o) ? sm[t - o] : 0;
            __syncthreads();
            sm[t] += add;
            __syncthreads();
        }
        int excl = sm[t] - c;
        int node = b * 256 + t;
        if (node < N_NODES) {
            off[node] = gbase + excl;
            deg[node] = c;
            inv_deg[node] = 1.0f / (float)c;    // deg >= 1 by construction
        }
        __syncthreads();
        hist[t] = gbase + excl;                 // per-col cursor
        __syncthreads();
        i = t;
        for (; i + 768 < cnt; i += 1024) {
            unsigned e0 = temp[tbase + i], e1 = temp[tbase + i + 256];
            unsigned e2 = temp[tbase + i + 512], e3 = temp[tbase + i + 768];
            int p0 = atomicAdd(&hist[e0 >> 16], 1);
            int p1 = atomicAdd(&hist[e1 >> 16], 1);
            int p2 = atomicAdd(&hist[e2 >> 16], 1);
            int p3 = atomicAdd(&hist[e3 >> 16], 1);
            csr[p0] = (ushort_t)e0; csr[p1] = (ushort_t)e1;
            csr[p2] = (ushort_t)e2; csr[p3] = (ushort_t)e3;
        }
        for (; i < cnt; i += 256) {
            unsigned e = temp[tbase + i];
            int p = atomicAdd(&hist[e >> 16], 1);
            csr[p] = (ushort_t)e;
        }
    } else {
        // layer 0: inv_deg not yet available (computed concurrently) -> Pj unscaled; A from f32 x
        gemm_tile3<true>((blockIdx.x - NBUCKET) * 64, lds.Bs, xf, Wb, nullptr, Plb, Pi_, Pj8);
    }
}

// ---------- standalone GEMM (layer 1): A from bf16 xb, inv_deg available -> Pj pre-scaled ----------
__global__ __launch_bounds__(256) void k_gemm(const ushort_t* __restrict__ xb,
                                              const ushort_t* __restrict__ Wl,
                                              const float* __restrict__ inv_deg,
                                              ushort_t* __restrict__ Plb,
                                              ushort_t* __restrict__ Pi_,
                                              unsigned char* __restrict__ Pj8) {
    __shared__ __align__(16) ushort_t Bs[128][136];
    gemm_tile3<false>(blockIdx.x * 64, Bs, xb, Wl, inv_deg, Plb, Pi_, Pj8);
}

// ---------- aggregation + exact GELU.
// Single fully-predicated 32-edge batch per iteration (8 groups x 4 edges): ALL gathers for
// a node issue together (8 uint2 loads in flight) -> one memory round-trip for deg<=32
// (P ~ 0.9998 under Poisson(16)). Inactive groups clamp to last edge (L1-hit broadcast)
// with weight 0 -> exact sums preserved. Flat unguarded arithmetic (R10 lesson: per-slot
// wave-uniform guards re-serialize the batched s_waitcnt and cost ~5us).
template<int LAYER0>
__device__ __forceinline__ void agg_body(const ushort_t* __restrict__ Plb,
                                         const ushort_t* __restrict__ Pi_,
                                         const unsigned char* __restrict__ Pj8,
                                         const int* __restrict__ off,
                                         const int* __restrict__ deg,
                                         const ushort_t* __restrict__ csr,
                                         const float* __restrict__ inv_deg,
                                         const float* __restrict__ bias,
                                         float* __restrict__ s_arr,
                                         float* __restrict__ out_f32,
                                         ushort_t* __restrict__ out_bf16) {
    int wv = __builtin_amdgcn_readfirstlane(threadIdx.x >> 6);   // wave-uniform node
    int node = blockIdx.x * 4 + wv;
    if (node >= N_NODES) return;
    const int lane = threadIdx.x & 63;
    const int g = lane >> 4;      // edge slot within quad
    const int q8 = lane & 15;     // element octet
    const int eoff = 8 * q8 + 2 * g;
    unsigned ulin = *(const unsigned*)(Plb + (size_t)node * D + eoff);
    unsigned upi  = *(const unsigned*)(Pi_ + (size_t)node * D + eoff);
    float2 bv = *(const float2*)(bias + eoff);
    float su[8];
    #pragma unroll
    for (int k = 0; k < 8; ++k) su[k] = 0.f;
    float sd = 0.f;
    const int e0 = off[node], ne = deg[node];
    for (int j = 0; j < ne; j += 32) {
        int sx[8];
        float wt[8];
        #pragma unroll
        for (int t = 0; t < 8; ++t) {
            int idx = j + 4 * t + g;
            bool a = idx < ne;
            sx[t] = csr[e0 + (a ? idx : ne - 1)];
            wt[t] = a ? 1.f : 0.f;
        }
        uint2 uu[8];
        #pragma unroll
        for (int t = 0; t < 8; ++t) uu[t] = *(const uint2*)(Pj8 + (size_t)sx[t] * D + 8 * q8);
        float dv[8];
        if (LAYER0) {
            #pragma unroll
            for (int t = 0; t < 8; ++t) dv[t] = inv_deg[sx[t]] * wt[t];
        } else {
            #pragma unroll
            for (int t = 0; t < 8; ++t) dv[t] = wt[t];
        }
        #pragma unroll
        for (int t = 0; t < 8; ++t) {
            f32x2 f0 = __builtin_amdgcn_cvt_pk_f32_fp8((int)uu[t].x, false);
            f32x2 f1 = __builtin_amdgcn_cvt_pk_f32_fp8((int)uu[t].x, true);
            f32x2 f2 = __builtin_amdgcn_cvt_pk_f32_fp8((int)uu[t].y, false);
            f32x2 f3 = __builtin_amdgcn_cvt_pk_f32_fp8((int)uu[t].y, true);
            if (LAYER0) sd += dv[t];
            su[0] += dv[t] * f0[0]; su[1] += dv[t] * f0[1];
            su[2] += dv[t] * f1[0]; su[3] += dv[t] * f1[1];
            su[4] += dv[t] * f2[0]; su[5] += dv[t] * f2[1];
            su[6] += dv[t] * f3[0]; su[7] += dv[t] * f3[1];
        }
    }
    // combine the 4 edge-groups: butterfly over lane bits 4 and 5
    #pragma unroll
    for (int k = 0; k < 8; ++k) {
        su[k] += __shfl_xor(su[k], 16);
        su[k] += __shfl_xor(su[k], 32);
    }
    float si;
    if (LAYER0) {
        sd += __shfl_xor(sd, 16);
        sd += __shfl_xor(sd, 32);
        si = sd;
        if (lane == 0) s_arr[node] = si;
    } else {
        si = s_arr[node];
    }
    float t0 = (g < 2) ? ((g == 0) ? su[0] : su[2]) : ((g == 2) ? su[4] : su[6]);
    float t1 = (g < 2) ? ((g == 0) ? su[1] : su[3]) : ((g == 2) ? su[5] : su[7]);
    float a0 = bf2f(ulin & 0xffffu) + bv.x - si * bf2f(upi & 0xffffu) - t0;
    float a1 = bf2f(ulin >> 16)     + bv.y - si * bf2f(upi >> 16)     - t1;
    float g0 = 0.5f * a0 * (1.0f + erff(a0 * 0.70710678118654752440f));
    float g1 = 0.5f * a1 * (1.0f + erff(a1 * 0.70710678118654752440f));
    if (LAYER0) {
        ushort_t tmp[2] = { f2bf(g0), f2bf(g1) };
        *(unsigned*)(out_bf16 + (size_t)node * D + eoff) = *(const unsigned*)tmp;
    } else {
        *(float2*)(out_f32 + (size_t)node * D + eoff) = make_float2(g0, g1);
    }
}

__global__ __launch_bounds__(256) void k_agg0(const ushort_t* __restrict__ Plb,
                                              const ushort_t* __restrict__ Pi_,
                                              const unsigned char* __restrict__ Pj8,
                                              const int* __restrict__ off,
                                              const int* __restrict__ deg,
                                              const ushort_t* __restrict__ csr,
                                              const float* __restrict__ inv_deg,
                                              const float* __restrict__ bias,
                                              float* __restrict__ s_arr,
                                              ushort_t* __restrict__ out_bf16) {
    agg_body<1>(Plb, Pi_, Pj8, off, deg, csr, inv_deg, bias, s_arr, nullptr, out_bf16);
}

__global__ __launch_bounds__(256) void k_agg1(const ushort_t* __restrict__ Plb,
                                              const ushort_t* __restrict__ Pi_,
                                              const unsigned char* __restrict__ Pj8,
                                              const int* __restrict__ off,
                                              const int* __restrict__ deg,
                                              const ushort_t* __restrict__ csr,
                                              const float* __restrict__ inv_deg,
                                              const float* __restrict__ bias,
                                              float* __restrict__ s_arr,
                                              float* __restrict__ out_f32) {
    agg_body<0>(Plb, Pi_, Pj8, off, deg, csr, inv_deg, bias, s_arr, out_f32, nullptr);
}

extern "C" void kernel_launch(void* const* d_in, const int* in_sizes, int n_in,
                              void* d_out, int out_size, void* d_ws, size_t ws_size,
                              hipStream_t stream) {
    const float* x      = (const float*)d_in[0];
    const int*   ei     = (const int*)d_in[1];
    const int*   rowp   = ei;
    const int*   colp   = ei + N_EDGES;
    const float* W1s    = (const float*)d_in[2];
    const float* W2s    = (const float*)d_in[3];
    const float* biases = (const float*)d_in[4];
    float* out = (float*)d_out;

    char* ws = (char*)d_ws;
    size_t o = 0;
    auto carve = [&](size_t bytes) -> void* {
        void* p = ws + o;
        o = (o + bytes + 255) & ~(size_t)255;
        return p;
    };
    int*           bucket_cursor = (int*)carve(NBUCKET * 4);
    int*           deg     = (int*)carve(N_NODES * 4);
    float*         inv_deg = (float*)carve(N_NODES * 4);
    int*           off     = (int*)carve(N_NODES * 4);
    float*         s_arr   = (float*)carve(N_NODES * 4);
    ushort_t*      csr     = (ushort_t*)carve((size_t)N_EDGES * 2);
    unsigned*      temp    = (unsigned*)carve((size_t)NBUCKET * CAP * 4);
    ushort_t*      xb      = (ushort_t*)carve((size_t)N_NODES * D * 2);
    ushort_t*      Wb      = (ushort_t*)carve((size_t)2 * 3 * 16384 * 2);
    ushort_t*      Plb     = (ushort_t*)carve((size_t)N_NODES * D * 2);
    ushort_t*      Pi_     = (ushort_t*)carve((size_t)N_NODES * D * 2);
    unsigned char* Pj8     = (unsigned char*)carve((size_t)N_NODES * D);
    if (o > ws_size) return;   // diagnostic: absmax would read exactly 10.875

    hipMemsetAsync(bucket_cursor, 0, NBUCKET * 4, stream);

    k_pre<<<SCAT_BLOCKS + WCONV_BLOCKS, 256, 0, stream>>>(rowp, colp, bucket_cursor, temp,
                                                          W1s, W2s, Wb);
    k_bsort_gemm<<<NBUCKET + GEMM_TILES, 256, 0, stream>>>(temp, bucket_cursor, csr, off,
                                                           deg, inv_deg, x, Wb, Plb, Pi_, Pj8);

    const int AB = (N_NODES + 3) / 4;
    k_agg0<<<AB, 256, 0, stream>>>(Plb, Pi_, Pj8, off, deg, csr, inv_deg, biases, s_arr, xb);
    k_gemm<<<GEMM_TILES, 256, 0, stream>>>(xb, Wb + (size_t)3 * 16384, inv_deg, Plb, Pi_, Pj8);
    k_agg1<<<AB, 256, 0, stream>>>(Plb, Pi_, Pj8, off, deg, csr, inv_deg, biases + 128, s_arr, out);
}